// Round 15
// baseline (33.399 us; speedup 1.0000x reference)
//
#include <hip/hip_runtime.h>
#include <hip/hip_bf16.h>

typedef short short8 __attribute__((ext_vector_type(8)));
typedef float f32x4 __attribute__((ext_vector_type(4)));

__device__ inline unsigned short f2bf(float f) {
    unsigned u = __builtin_bit_cast(unsigned, f);
    u += 0x7FFFu + ((u >> 16) & 1u);          // round-to-nearest-even
    return (unsigned short)(u >> 16);
}

__device__ inline void gload_lds16(const void* g, void* l) {
    __builtin_amdgcn_global_load_lds(
        (const __attribute__((address_space(1))) void*)g,
        (__attribute__((address_space(3))) void*)l, 16, 0, 0);
}

// ---------------------------------------------------------------------------
// prep: Wm[d][c] = 0.25 * sum_h Wv[h*64+d][c], packed in MFMA B-fragment order
// (proven R2-R13). bm[d] = 0.25 * sum_h bv[h*64+d].
// ---------------------------------------------------------------------------
__global__ __launch_bounds__(256)
void k_prep(const float* __restrict__ Wv, const float* __restrict__ bv,
            unsigned short* __restrict__ Bf, float* __restrict__ bm)
{
    const int t = blockIdx.x * 256 + threadIdx.x;   // 0..16383
    const int fi = t >> 9;
    const int lane = (t >> 3) & 63;
    const int j = t & 7;
    const int ct = fi >> 3, kc = fi & 7;
    const int d = ct * 16 + (lane & 15);
    const int c = kc * 32 + (lane >> 4) * 8 + j;
    const float s = 0.25f * (Wv[(size_t)d * 256 + c] +
                             Wv[(size_t)(64 + d) * 256 + c] +
                             Wv[(size_t)(128 + d) * 256 + c] +
                             Wv[(size_t)(192 + d) * 256 + c]);
    Bf[t] = f2bf(s);
    if (t < 64)
        bm[t] = 0.25f * (bv[t] + bv[64 + t] + bv[128 + t] + bv[192 + t]);
}

// ---------------------------------------------------------------------------
// main: R13 counted-vmcnt double-buffered gload_lds pipeline
//   + coalesced-store epilogue via Ot LDS bounce (4 KB contiguous per block)
//   + exact-divide persistent grid (1250 blocks x 5 tiles).
// R14 BUGFIX: Ot crosses barrier B, and raw s_barrier has NO implicit
// waitcnt — must emit s_waitcnt lgkmcnt(0) before it so all waves' ds_writes
// have landed (ISA §8: "s_waitcnt first if data dep!"). sched_barrier(0)
// pins so the scheduler can't hoist/sink LDS ops across the asm barrier.
// vmcnt pipeline untouched: never drains to 0 in-loop.
// ---------------------------------------------------------------------------
__global__ __launch_bounds__(256)
void k_main(const float* __restrict__ X, const unsigned short* __restrict__ Bf,
            const float* __restrict__ bm, float* __restrict__ out,
            int N, int ntiles)
{
    __shared__ float Xb[2][16][256];                // 32 KB X double-buffer
    __shared__ float Ot[16][68];                    // 4.25 KB out bounce

    const int t = threadIdx.x;
    const int wave = t >> 6, lane = t & 63;
    const int r = lane & 15, kgrp = lane >> 4;

    // per-wave B fragments (col-tile ct = wave) + bias, loaded once
    short8 bfr[8];
#pragma unroll
    for (int kc = 0; kc < 8; ++kc)
        bfr[kc] = *(const short8*)&Bf[((wave * 8 + kc) * 64 + lane) * 8];
    const float bias = bm[wave * 16 + r];

    asm volatile("s_waitcnt vmcnt(0)" ::: "memory"); // clean vm counter

    int tile = blockIdx.x;
    if (tile >= ntiles) return;                     // uniform block exit

    // prologue: stage tile -> buf 0 (4 gload_lds per wave, rows wave*4..+3)
#pragma unroll
    for (int j = 0; j < 4; ++j) {
        const int i = wave * 4 + j;
        int row = tile * 16 + i;
        if (row >= N) row = N - 1;
        const char* src = (const char*)(X + (size_t)row * 256)
                        + ((lane * 16) ^ ((i & 7) << 4));
        gload_lds16(src, (char*)&Xb[0][i][0]);
    }

    int cur = 0;
    for (; tile < ntiles; tile += gridDim.x) {
        const int nxt_tile = tile + gridDim.x;
        if (nxt_tile < ntiles) {
            // stage next tile into other buffer (outstanding stays >= 4)
#pragma unroll
            for (int j = 0; j < 4; ++j) {
                const int i = wave * 4 + j;
                int row = nxt_tile * 16 + i;
                if (row >= N) row = N - 1;
                const char* src = (const char*)(X + (size_t)row * 256)
                                + ((lane * 16) ^ ((i & 7) << 4));
                gload_lds16(src, (char*)&Xb[cur ^ 1][i][0]);
            }
            asm volatile("s_waitcnt vmcnt(4)" ::: "memory"); // cur's 4 done
        } else {
            asm volatile("s_waitcnt vmcnt(0)" ::: "memory"); // last: drain
        }
        __builtin_amdgcn_sched_barrier(0);
        __builtin_amdgcn_s_barrier();               // A: Xb[cur] visible
        __builtin_amdgcn_sched_barrier(0);

        // compute: A from LDS (swizzled), B from registers
        const char* rbase = (const char*)&Xb[cur][r][0];
        const int rx = (r & 7) << 4;
        f32x4 acc = {};
#pragma unroll
        for (int kc = 0; kc < 8; ++kc) {
            const int g0 = kgrp * 32 + kc * 128;
            const f32x4 x0 = *(const f32x4*)(rbase + ((g0) ^ rx));
            const f32x4 x1 = *(const f32x4*)(rbase + ((g0 + 16) ^ rx));
            short8 a;
            a[0] = (short)f2bf(x0[0]); a[1] = (short)f2bf(x0[1]);
            a[2] = (short)f2bf(x0[2]); a[3] = (short)f2bf(x0[3]);
            a[4] = (short)f2bf(x1[0]); a[5] = (short)f2bf(x1[1]);
            a[6] = (short)f2bf(x1[2]); a[7] = (short)f2bf(x1[3]);
            acc = __builtin_amdgcn_mfma_f32_16x16x32_bf16(a, bfr[kc], acc, 0, 0, 0);
        }

        // acc -> Ot (C/D: row = kgrp*4+j, col = wave*16+r)
#pragma unroll
        for (int j = 0; j < 4; ++j)
            Ot[kgrp * 4 + j][wave * 16 + r] = acc[j] + bias;

        // ---- FIX: drain LDS writes before the execution-only barrier ----
        asm volatile("s_waitcnt lgkmcnt(0)" ::: "memory");
        __builtin_amdgcn_sched_barrier(0);
        __builtin_amdgcn_s_barrier();               // B: Ot ready, Xb reads done
        __builtin_amdgcn_sched_barrier(0);

        // coalesced store: thread t -> row t>>4, cols (t&15)*4..+4
        // 256 threads x 16 B = one contiguous 4 KB block
        {
            const int row = t >> 4, c4 = t & 15;
            const f32x4 v = *(const f32x4*)&Ot[row][c4 * 4];
            const int grow = tile * 16 + row;
            if (grow < N)
                *(f32x4*)&out[(size_t)grow * 64 + c4 * 4] = v;
        }
        __builtin_amdgcn_sched_barrier(0);          // keep Ot read before next A

        cur ^= 1;
    }
}

extern "C" void kernel_launch(void* const* d_in, const int* in_sizes, int n_in,
                              void* d_out, int out_size, void* d_ws, size_t ws_size,
                              hipStream_t stream)
{
    const float* sx = (const float*)d_in[1];        // source_input
    const float* Wv = (const float*)d_in[6];
    const float* bv = (const float*)d_in[7];
    float* out = (float*)d_out;

    unsigned short* Bf = (unsigned short*)d_ws;                 // 32 KB
    float* bm = (float*)((char*)d_ws + 32768);                  // 256 B

    const int N = in_sizes[0] / 256;
    const int ntiles = (N + 15) / 16;
    const int nblk = ntiles < 1250 ? ntiles : 1250; // 6250 = 1250 x 5 exact

    k_prep<<<64, 256, 0, stream>>>(Wv, bv, Bf, bm);
    k_main<<<nblk, 256, 0, stream>>>(sx, Bf, bm, out, N, ntiles);
}